// Round 2
// baseline (171.533 us; speedup 1.0000x reference)
//
#include <hip/hip_runtime.h>
#include <hip/hip_bf16.h>

// B=2, M=2048, HID=1024, NH=16, D=64.  No softmax in the reference, so
//   out = ((h Wq^T)(h Wk^T)^T (h Wv^T)) Wo^T
// reassociates twice:  S_{b,h} = K_h^T V_h  (64x64), and
//   out_b = Q_b @ T_b   with  T_b[h*64+d, n] = sum_j S_{b,h}[d,j] Wo[n, h*64+j]
//
// Dtypes: inputs fp32, d_out fp32; internal bf16 with fp32 accumulate
// (rounds 3-10: absmax 3-4 vs threshold 11.68).
//
// Round-13: r12's 256^2 8-phase gemm1 FAILED (absmax 292) from a vmcnt/
// barrier race: the counted vmcnt was placed at the TOP of the consuming
// phase, directly before its ds_reads.  vmcnt is per-wave: it proves only
// the waiting wave's own global_load_lds landed, while the LDS region is
// staged by all 8 waves -- the wait must precede a BARRIER and the reads
// must follow it.  Also: no prologue wait+barrier, and conditional stages
// inside the loop shifted the tail vmcnt arithmetic.
// r13 keeps the identical layout/swizzle/staging geometry and fixes only
// the schedule:
//   prologue: 12 loads, vmcnt(8), barrier
//   phase:    ds_read | stage | barrier | lgkmcnt(0)+sched_barrier |
//             setprio(1) 16xMFMA setprio(0) | vmcnt(N) | barrier
//   steady:   VW(6) at P0, VW(8) at P3 only (per-wave ordinal-tracked);
//   tail:     kt=14 peeled (VW(6)/VW(4)), kt=15 peeled (VW(0) then none).
// WAR: every region overwrite is behind prior readers' lgkmcnt(0)+barrier.
// Lessons kept: no dense-reduction atomics (r6->r7); XOR swizzle + BK=64
// (r6); gemm2 BM=64 -> 2 blocks/CU (r9); never trade high-occupancy FLOPs
// for low-occupancy FLOPs (r8); price redundant re-reads by XCD locality
// (r10); vmcnt waits are per-wave -- barrier before cross-wave reads (r12).
//
// Pipeline:
//   0. prep: h->hb (bf16), Wq|Wk|Wv->wcat (bf16)
//   1. QKVb = hb @ wcat^T        (4096x3072 bf16)            [MFMA GEMM 256^2]
//   2. Spart[bh,c] = K^T V partial over 128 rows             [VALU]
//   2b. S = sum_c Spart          (each line read once)       [BW]
//   3. Tt[b][n,k] = (S_h Wo_h^T)^T  (2 x 1024x1024 bf16)     [VALU]
//   4. out = Q @ Tt_b^T          (4096x1024 fp32 -> d_out)   [MFMA GEMM]

typedef unsigned short u16;
typedef unsigned int u32;
typedef __attribute__((ext_vector_type(8))) short bf16x8;
typedef __attribute__((ext_vector_type(4))) float f32x4;

__device__ __forceinline__ void async_copy16(void* lds, const void* g) {
  __builtin_amdgcn_global_load_lds((const __attribute__((address_space(1))) void*)g,
                                   (__attribute__((address_space(3))) void*)lds,
                                   16, 0, 0);
}

__device__ __forceinline__ u16 f2bf(float f) {
  union { __hip_bfloat16 h; u16 u; } c;
  c.h = __float2bfloat16(f);
  return c.u;
}
__device__ __forceinline__ float bflo(u32 w) {
  union { u32 u; float f; } c; c.u = w << 16; return c.f;
}
__device__ __forceinline__ float bfhi(u32 w) {
  union { u32 u; float f; } c; c.u = w & 0xFFFF0000u; return c.f;
}
__device__ __forceinline__ ushort4 cvt4(float4 v) {
  ushort4 o; o.x = f2bf(v.x); o.y = f2bf(v.y); o.z = f2bf(v.z); o.w = f2bf(v.w);
  return o;
}

// ---------------------------------------------------------------- prep ------
__global__ __launch_bounds__(256) void prep(const float4* __restrict__ h,
                                            const float4* __restrict__ wq,
                                            const float4* __restrict__ wk,
                                            const float4* __restrict__ wv,
                                            ushort4* __restrict__ hb,
                                            ushort4* __restrict__ wcat) {
  int i = blockIdx.x * 256 + threadIdx.x;  // float4 units
  if (i < 1048576) { hb[i] = cvt4(h[i]); return; }          // h: 4096x1024
  i -= 1048576;
  if (i < 262144) { wcat[i] = cvt4(wq[i]); return; }
  i -= 262144;
  if (i < 262144) { wcat[262144 + i] = cvt4(wk[i]); return; }
  i -= 262144;
  wcat[524288 + i] = cvt4(wv[i]);
}

// ------------------------------------------------- 256^2 8-phase NT GEMM ----
// C[m,n] = sum_k A[m*1024+k] * B[n*1024+k], M=4096, N=3072, K=1024, bf16 out.
// 512 threads = 8 waves (2 Mhalves x 4 Ncols), per-wave C = 128x64.
// LDS XOR swizzle: LDS(row, g) holds global 16B-group g ^ (row&7); applied
// on the global-source side so global_load_lds dest stays linear.

#define VW(N) asm volatile("s_waitcnt vmcnt(" #N ")" ::: "memory")
#define NOPW ((void)0)

// phase: quadrant (MH,NH) of buf `cur`.
//   ds_read | STAGE | barrier | lgkmcnt(0)+sched_barrier | MFMA | VWAIT | barrier
#define GPHASE(MH, NH, STAGE, VWAIT)                                         \
  do {                                                                       \
    bf16x8 af[4][2], bv[2][2];                                               \
    const u16* Ab = &Als[cur][(wm + (MH) * 64) * 64];                        \
    const u16* Bb = &Bls[cur][(wn + (NH) * 32) * 64];                        \
    _Pragma("unroll") for (int i = 0; i < 4; ++i) {                          \
      af[i][0] = *(const bf16x8*)(Ab + i * 1024 + aoff0);                    \
      af[i][1] = *(const bf16x8*)(Ab + i * 1024 + aoff1);                    \
    }                                                                        \
    _Pragma("unroll") for (int j = 0; j < 2; ++j) {                          \
      bv[j][0] = *(const bf16x8*)(Bb + j * 1024 + aoff0);                    \
      bv[j][1] = *(const bf16x8*)(Bb + j * 1024 + aoff1);                    \
    }                                                                        \
    STAGE;                                                                   \
    __builtin_amdgcn_s_barrier();                                            \
    asm volatile("s_waitcnt lgkmcnt(0)" ::: "memory");                       \
    __builtin_amdgcn_sched_barrier(0);                                       \
    __builtin_amdgcn_s_setprio(1);                                           \
    _Pragma("unroll") for (int i = 0; i < 4; ++i)                            \
        _Pragma("unroll") for (int j = 0; j < 2; ++j)                        \
            acc[(MH) * 4 + i][(NH) * 2 + j] =                                \
                __builtin_amdgcn_mfma_f32_16x16x32_bf16(                     \
                    af[i][0], bv[j][0], acc[(MH) * 4 + i][(NH) * 2 + j],     \
                    0, 0, 0);                                                \
    _Pragma("unroll") for (int i = 0; i < 4; ++i)                            \
        _Pragma("unroll") for (int j = 0; j < 2; ++j)                        \
            acc[(MH) * 4 + i][(NH) * 2 + j] =                                \
                __builtin_amdgcn_mfma_f32_16x16x32_bf16(                     \
                    af[i][1], bv[j][1], acc[(MH) * 4 + i][(NH) * 2 + j],     \
                    0, 0, 0);                                                \
    __builtin_amdgcn_s_setprio(0);                                           \
    VWAIT;                                                                   \
    __builtin_amdgcn_s_barrier();                                            \
  } while (0)

__global__ __launch_bounds__(512, 2) void gemm256(const u16* __restrict__ A,
                                                  const u16* __restrict__ B,
                                                  u16* __restrict__ C) {
  __shared__ u16 Als[2][16384];   // [buf][256 rows x 64 k]  (32 KiB each)
  __shared__ u16 Bls[2][16384];
  const int t = threadIdx.x;
  const int lane = t & 63;
  const int wave = t >> 6;                 // 0..7
  const int wm = (wave >> 2) * 128;        // 0 / 128
  const int wn = (wave & 3) * 64;          // 0,64,128,192
  const int lrow = lane & 15;
  const int quad = lane >> 4;

  // bijective XCD swizzle (192 blocks, 192%8==0): XCD x -> m-panels {2x,2x+1}
  const int bid = blockIdx.x;
  const int xcd = bid & 7;
  const int c8 = bid >> 3;                 // 0..23
  const int m0 = (xcd * 2 + (c8 >= 12 ? 1 : 0)) * 256;
  const int n0 = (c8 >= 12 ? c8 - 12 : c8) * 256;

  // staging: per inst, wave stages 1KB = 8 rows; lane l -> row rowb+(l>>3),
  // LDS 16B-group l&7 holding global group (l&7)^(l>>3) (rowb%8==0).
  const int lro = lane >> 3;
  const int lgrp = (lane & 7) ^ lro;
  const u16* Ag = A + (size_t)(m0 + lro) * 1024 + lgrp * 8;
  const u16* Bg = B + (size_t)(n0 + lro) * 1024 + lgrp * 8;
  const int lds_t = lane * 8;              // u16 units = lane*16B

  // ds_read offsets: rows read have row&7 == lrow&7 (all row bases %16==0)
  const int sw = lrow & 7;
  const int aoff0 = lrow * 64 + ((quad + 0) ^ sw) * 8;   // k-half 0 (k 0..31)
  const int aoff1 = lrow * 64 + ((quad + 4) ^ sw) * 8;   // k-half 1 (k 32..63)

  f32x4 acc[8][4];
#pragma unroll
  for (int i = 0; i < 8; ++i)
#pragma unroll
    for (int j = 0; j < 4; ++j) acc[i][j] = {0.f, 0.f, 0.f, 0.f};

  // stage one 16KB half-region (2 insts/thread).
  // A half h = rows {h*64..+63, 128+h*64..+63}  (quadrant MH=h readers).
  auto stA = [&](int buf, int h, int kt) {
#pragma unroll
    for (int j = 0; j < 2; ++j) {
      const int cx = wave * 2 + j;
      const int rowb = h * 64 + (cx & 7) * 8 + (cx >> 3) * 128;
      async_copy16(&Als[buf][rowb * 64 + lds_t], Ag + (size_t)rowb * 1024 + kt * 64);
    }
  };
  // B half h = rows with (r&63) in [32h, 32h+32)  (quadrant NH=h readers).
  auto stB = [&](int buf, int h, int kt) {
#pragma unroll
    for (int j = 0; j < 2; ++j) {
      const int cx = wave * 2 + j;
      const int rowb = h * 32 + (cx >> 2) * 64 + (cx & 3) * 8;
      async_copy16(&Bls[buf][rowb * 64 + lds_t], Bg + (size_t)rowb * 1024 + kt * 64);
    }
  };

  // prologue: 12 loads/thread; wait own first 4 (A-low0,B-low0), barrier.
  stA(0, 0, 0); stB(0, 0, 0); stA(0, 1, 0); stB(0, 1, 0);
  stA(1, 0, 1); stB(1, 0, 1);
  VW(8);
  __builtin_amdgcn_s_barrier();

  // Steady state per-wave vmcnt ledger (2 loads per stage call):
  //  P0 stages A-high(kt+1); after it 10 in flight; VW(6) waits the 4
  //     covering A-high(kt)+B-high(kt)  -> P1/P2/P3 reads of kt.
  //  P3 stages B-low(kt+2); 12 in flight; VW(8) waits the 4 covering
  //     A-low(kt+1)+B-low(kt+1)         -> P0 reads of kt+1.
  int cur = 0;
#pragma unroll 1
  for (int kt = 0; kt < 14; ++kt) {
    const int nxt = cur ^ 1;
    GPHASE(0, 0, stA(nxt, 1, kt + 1), VW(6));
    GPHASE(0, 1, stB(nxt, 1, kt + 1), NOPW);
    GPHASE(1, 0, stA(cur, 0, kt + 2), NOPW);
    GPHASE(1, 1, stB(cur, 0, kt + 2), VW(8));
    cur = nxt;
  }
  // kt = 14  (cur == 0): stage only kt=15's high halves.
  GPHASE(0, 0, stA(1, 1, 15), VW(6));
  GPHASE(0, 1, stB(1, 1, 15), NOPW);
  GPHASE(1, 0, NOPW,          NOPW);
  GPHASE(1, 1, NOPW,          VW(4));   // waits A-low15,B-low15
  cur = 1;
  // kt = 15: drain.
  GPHASE(0, 0, NOPW, VW(0));            // waits A-high15,B-high15
  GPHASE(0, 1, NOPW, NOPW);
  GPHASE(1, 0, NOPW, NOPW);
  GPHASE(1, 1, NOPW, NOPW);

  // C/D layout (verified m89/m91): col = lane&15, row = (lane>>4)*4 + r
  const int crow0 = m0 + wm + quad * 4;
  const int ccol0 = n0 + wn + lrow;
#pragma unroll
  for (int mf = 0; mf < 8; ++mf)
#pragma unroll
    for (int nf = 0; nf < 4; ++nf)
#pragma unroll
      for (int r = 0; r < 4; ++r)
        C[(size_t)(crow0 + mf * 16 + r) * 3072 + ccol0 + nf * 16] =
            f2bf(acc[mf][nf][r]);
}

// ------------------------------------------------------------- NT GEMM ------
// (kept for gemm2)  C[m,n] = sum_k A[m*lda+k] * B[n*K+k].
template <bool BF16_OUT, int BM, int BN>
__global__ __launch_bounds__(256) void gemm_bt(const u16* __restrict__ A, int lda,
                                               const u16* __restrict__ B0,
                                               const u16* __restrict__ B1,
                                               void* __restrict__ Cv,
                                               int N, int K) {
  constexpr int WR = BM / 64;       // wave rows (2 or 1)
  constexpr int WC = 4 / WR;        // wave cols (2 or 4)
  constexpr int NI = BN / WC / 16;  // 16-col MFMA tiles per wave
  __shared__ u16 Als[BM * 64];
  __shared__ u16 Bls[BN * 64];
  const int t = threadIdx.x;
  const int lane = t & 63;
  const int wave = t >> 6;
  const int wm = (wave / WC) * 64;
  const int wn = (wave % WC) * (BN / WC);
  const int lrow = lane & 15;      // MFMA m/n index
  const int quad = lane >> 4;      // MFMA k-group (16-B units)
  const int m0 = blockIdx.y * BM;
  const int n0 = blockIdx.x * BN;
  const u16* B = (B1 != nullptr && m0 >= 2048) ? B1 : B0;

  const int srow = t >> 3;
  const int scol = (((t & 7) ^ (srow & 7)) * 8);
  const u16* Ag0 = A + (size_t)(m0 + srow) * lda + scol;
  const u16* Bg0 = B + (size_t)(n0 + srow) * K + scol;
  u16* Al0 = Als + t * 8;  // + c*2048 u16 per copy (32 rows)
  u16* Bl0 = Bls + t * 8;

  f32x4 acc[4][NI];
#pragma unroll
  for (int i = 0; i < 4; ++i)
#pragma unroll
    for (int j = 0; j < NI; ++j) acc[i][j] = {0.f, 0.f, 0.f, 0.f};

  for (int k0 = 0; k0 < K; k0 += 64) {
#pragma unroll
    for (int c = 0; c < BM / 32; ++c)
      async_copy16(Al0 + c * 2048, Ag0 + (size_t)(c * 32) * lda + k0);
#pragma unroll
    for (int c = 0; c < BN / 32; ++c)
      async_copy16(Bl0 + c * 2048, Bg0 + (size_t)(c * 32) * K + k0);
    __syncthreads();

#pragma unroll
    for (int half = 0; half < 2; ++half) {
      const int gg = quad + half * 4;  // global k-group within BK=64
      bf16x8 af[4], bfv[NI];
#pragma unroll
      for (int i = 0; i < 4; ++i) {
        const int ra = wm + i * 16 + lrow;
        af[i] = *(const bf16x8*)(Als + ra * 64 + ((gg ^ (ra & 7)) << 3));
      }
#pragma unroll
      for (int i = 0; i < NI; ++i) {
        const int rb = wn + i * 16 + lrow;
        bfv[i] = *(const bf16x8*)(Bls + rb * 64 + ((gg ^ (rb & 7)) << 3));
      }
#pragma unroll
      for (int mi = 0; mi < 4; ++mi)
#pragma unroll
        for (int ni = 0; ni < NI; ++ni)
          acc[mi][ni] = __builtin_amdgcn_mfma_f32_16x16x32_bf16(
              af[mi], bfv[ni], acc[mi][ni], 0, 0, 0);
    }
    __syncthreads();
  }

  const int crow0 = m0 + wm + (lane >> 4) * 4;
  const int ccol0 = n0 + wn + (lane & 15);
#pragma unroll
  for (int mi = 0; mi < 4; ++mi)
#pragma unroll
    for (int ni = 0; ni < NI; ++ni) {
      const int col = ccol0 + ni * 16;
#pragma unroll
      for (int r = 0; r < 4; ++r) {
        const size_t idx = (size_t)(crow0 + mi * 16 + r) * N + col;
        if (BF16_OUT) ((u16*)Cv)[idx]   = f2bf(acc[mi][ni][r]);
        else          ((float*)Cv)[idx] = acc[mi][ni][r];
      }
    }
}

// --------------------------------------------- Spart = partial K^T V --------
__global__ __launch_bounds__(256) void s_kernel(const u16* __restrict__ QKV,
                                                float* __restrict__ Spart) {
  const int bh = blockIdx.x;
  const int b = bh >> 4, hh = bh & 15;
  const int row0 = b * 2048 + blockIdx.y * 128;
  const u16* Kg = QKV + (size_t)row0 * 3072 + 1024 + hh * 64;

  __shared__ float Ks[64][64];
  __shared__ float Vs[64][64];
  const int t = threadIdx.x;
  const int lr = t >> 2;        // 0..63 row within stage
  const int lc = (t & 3) * 16;  // col group (16 cols)
  const int d1 = (t >> 4) * 4;
  const int d2 = (t & 15) * 4;

  float acc[4][4] = {};

  for (int r0 = 0; r0 < 128; r0 += 64) {
    const u16* kp = Kg + (size_t)(r0 + lr) * 3072 + lc;
    const uint4 kw0 = *(const uint4*)kp;
    const uint4 kw1 = *(const uint4*)(kp + 8);
    const uint4 vw0 = *(const uint4*)(kp + 1024);  // V = K + 1024 cols
    const uint4 vw1 = *(const uint4*)(kp + 1032);
    __syncthreads();  // prev-iter readers done
    float* kd = &Ks[lr][lc];
    *(float4*)(kd)      = float4{bflo(kw0.x), bfhi(kw0.x), bflo(kw0.y), bfhi(kw0.y)};
    *(float4*)(kd + 4)  = float4{bflo(kw0.z), bfhi(kw0.z), bflo(kw0.w), bfhi(kw0.w)};
    *(float4*)(kd + 8)  = float4{bflo(kw1.x), bfhi(kw1.x), bflo(kw1.y), bfhi(kw1.y)};
    *(float4*)(kd + 12) = float4{bflo(kw1.z), bfhi(kw1.z), bflo(kw1.w), bfhi(kw1.w)};
    float* vd = &Vs[lr][lc];
    *(float4*)(vd)      = float4{bflo(vw0.x), bfhi(vw0.x), bflo(vw0.y), bfhi(vw0.y)};
    *(float4*)(vd + 4)  = float4{bflo(vw0.z), bfhi(vw0.z), bflo(vw0.w), bfhi(vw0.w)};
    *(float4*)(vd + 8)  = float4{bflo(vw1.x), bfhi(vw1.x), bflo(vw1.y), bfhi(vw1.y)};
    *(float4*)(vd + 12) = float4{bflo(vw1.z), bfhi(vw1.z), bflo(vw1.w), bfhi(vw1.w)};
    __syncthreads();
#pragma unroll
    for (int r = 0; r < 64; ++r) {
      float kv[4], vv[4];
      *(float4*)kv = *(const float4*)&Ks[r][d1];
      *(float4*)vv = *(const float4*)&Vs[r][d2];
#pragma unroll
      for (int i = 0; i < 4; ++i)
#pragma unroll
        for (int j = 0; j < 4; ++j) acc[i][j] += kv[i] * vv[j];
    }
  }
  float* Sp = Spart + ((size_t)bh * 16 + blockIdx.y) * 4096;
#pragma unroll
  for (int i = 0; i < 4; ++i)
    *(float4*)&Sp[(d1 + i) * 64 + d2] =
        float4{acc[i][0], acc[i][1], acc[i][2], acc[i][3]};
}

// ---------------------------------------------------- S = sum_c Spart -------
__global__ __launch_bounds__(256) void reduce_s(const float4* __restrict__ Spart,
                                                float4* __restrict__ S) {
  const int g = blockIdx.x * 256 + threadIdx.x;  // 0..32767
  const int bh = g >> 10, j = g & 1023;
  const float4* p = Spart + (size_t)bh * 16384 + j;  // 16 chunks * 1024 f4
  float4 a = {0.f, 0.f, 0.f, 0.f};
#pragma unroll
  for (int c = 0; c < 16; ++c) {
    const float4 v = p[(size_t)c * 1024];
    a.x += v.x; a.y += v.y; a.z += v.z; a.w += v.w;
  }
  S[g] = a;
}

// ------------------------------------------- Tt = (S_h Wo_h^T)^T ------------
__global__ __launch_bounds__(256) void t_kernel(const float* __restrict__ S,
                                                const float* __restrict__ Wo,
                                                u16* __restrict__ Tt) {
  const int n0 = blockIdx.x * 128;
  const int hh = blockIdx.y;
  const int b  = blockIdx.z;
  __shared__ float Ss[64][68];
  __shared__ float Ws[128][68];
  const int t = threadIdx.x;
  {
    const float* sg = S + (size_t)(b * 16 + hh) * 4096 + (t >> 2) * 64 + (t & 3) * 16;
    float* sd = &Ss[t >> 2][(t & 3) * 16];
#pragma unroll
    for (int i = 0; i < 4; ++i) *(float4*)(sd + 4 * i) = *(const float4*)(sg + 4 * i);
    const float* wg = Wo + (size_t)(n0 + (t >> 1)) * 1024 + hh * 64 + (t & 1) * 32;
    float* wd = &Ws[t >> 1][(t & 1) * 32];
#pragma unroll
    for (int i = 0; i < 8; ++i) *(float4*)(wd + 4 * i) = *(const float4*)(wg + 4 * i);
  }
  __syncthreads();

  const int td = (t >> 4) * 4;  // d = td..td+3
  const int tn = t & 15;        // n = n0 + tn + 16k
  float acc[4][8] = {};
  for (int jj = 0; jj < 64; jj += 4) {
    float4 sv[4], wv[8];
#pragma unroll
    for (int i = 0; i < 4; ++i) sv[i] = *(const float4*)&Ss[td + i][jj];
#pragma unroll
    for (int k = 0; k < 8; ++k) wv[k] = *(const float4*)&Ws[tn + 16 * k][jj];
#pragma unroll
    for (int i = 0; i < 4; ++i)
#pragma unroll
      for (int k = 0; k < 8; ++k)
        acc[i][k] += sv[i].x * wv[k].x + sv[i].y * wv[k].y +
                     sv[i].z * wv[k].z + sv[i].w * wv[k].w;
  }

  u16* tp = Tt + (size_t)b * 1048576;
#pragma unroll
  for (int k = 0; k < 8; ++k) {
    const int n = n0 + tn + 16 * k;
    ushort4 o;
    o.x = f2bf(acc[0][k]); o.y = f2bf(acc[1][k]);
    o.z = f2bf(acc[2][k]); o.w = f2bf(acc[3][k]);
    *(ushort4*)&tp[(size_t)n * 1024 + hh * 64 + td] = o;
  }
}

// ---------------------------------------------------------------------------
extern "C" void kernel_launch(void* const* d_in, const int* in_sizes, int n_in,
                              void* d_out, int out_size, void* d_ws, size_t ws_size,
                              hipStream_t stream) {
  const float* h  = (const float*)d_in[0];  // (4096, 1024) fp32
  // d_in[1] = key_pe: dead branch in reference, unused.
  const float* Wq = (const float*)d_in[2];
  const float* Wk = (const float*)d_in[3];
  const float* Wv = (const float*)d_in[4];
  const float* Wo = (const float*)d_in[5];

  char* ws = (char*)d_ws;
  u16*   hb    = (u16*)(ws);                    // 4096*1024*2 = 8 MiB @ 0
  u16*   wcat  = (u16*)(ws + (8ull  << 20));    // 3072*1024*2 = 6 MiB
  u16*   QKVb  = (u16*)(ws + (16ull << 20));    // 4096*3072*2 = 24 MiB
  float* S     = (float*)(ws + (40ull << 20));  // 32*64*64*4  = 0.5 MiB
  u16*   Tt    = (u16*)(ws + (41ull << 20));    // 2*1024*1024*2 = 4 MiB
  float* Spart = (float*)(ws + (48ull << 20));  // 512*64*64*4 = 8 MiB
  // total ws use: 56 MiB (ws_size = 256 MiB)

  prep<<<7168, 256, 0, stream>>>((const float4*)h, (const float4*)Wq,
                                 (const float4*)Wk, (const float4*)Wv,
                                 (ushort4*)hb, (ushort4*)wcat);
  // QKVb = hb @ wcat^T : (4096 x 3072), K=1024, 192 blocks (1/CU, 8 waves)
  gemm256<<<192, 512, 0, stream>>>(hb, wcat, QKVb);
  s_kernel<<<dim3(32, 16), 256, 0, stream>>>(QKVb, Spart);
  reduce_s<<<128, 256, 0, stream>>>((const float4*)Spart, (float4*)S);
  t_kernel<<<dim3(8, 16, 2), 256, 0, stream>>>(S, Wo, Tt);
  // out = Q @ Tt_b^T : (4096 x 1024), K=1024, BM=64 -> 512 blocks = 2/CU
  gemm_bt<false, 64, 128><<<dim3(8, 64), 256, 0, stream>>>(
      QKVb, 3072, Tt, Tt + 1048576, d_out, 1024, 1024);
}

// Round 3
// 157.085 us; speedup vs baseline: 1.0920x; 1.0920x over previous
//
#include <hip/hip_runtime.h>
#include <hip/hip_bf16.h>

// B=2, M=2048, HID=1024, NH=16, D=64.  No softmax in the reference, so
//   out = ((h Wq^T)(h Wk^T)^T (h Wv^T)) Wo^T
// reassociates twice:  S_{b,h} = K_h^T V_h  (64x64), and
//   out_b = Q_b @ T_b   with  T_b[h*64+d, n] = sum_j S_{b,h}[d,j] Wo[n, h*64+j]
//
// Dtypes: inputs fp32, d_out fp32; internal bf16 with fp32 accumulate.
//
// Round-14: r13's 4-quadrant 8-phase gemm256 passed (absmax 4) but measured
// 50us, WORSE than the 40us gemm_bt it replaced: 64 phases x ~1700cyc, with
// 2x LDS re-read of every fragment (48 ds_read_b128/wave/K-tile) and 128
// lockstep barriers; MfmaUtil 18.9%.  r14 restructures gemm1 to BK=32 with
// a 4-buffer rotation and ONE phase per K-tile:
//   {12 ds_read_b128 (each frag read once) | 4 global_load_lds staging tile
//    kt+3 into buf (kt+3)&3 | lgkmcnt(0) | 32 MFMA (setprio) | vmcnt(8) |
//    s_barrier}
// 32 phases, 32 barriers, LDS traffic halved, uniform 3-tile prefetch depth
// (slack ~3 phases > HBM latency), vmcnt never drained mid-loop.
// Single-barrier safety: read buf kt&3 vs stage buf (kt+3)&3 are always
// distinct; each wave's ds_reads complete (own lgkmcnt(0)) before its
// barrier, so post-barrier WAR overwrites of retired buffers are safe; tile
// kt+1 is gated by all waves' VW(8)+barrier at end of phase kt.
// Swizzle (4 granules/row): store global granule (l&3)^((l>>3)&3) at slot
// l&3 (linear global_load_lds dest); read slot quad^((lrow>>1)&3).
// Lessons kept: no dense-reduction atomics (r6->r7); gemm2 BM=64 -> 2
// blocks/CU (r9); never trade high-occupancy FLOPs for low-occupancy FLOPs
// (r8); price redundant re-reads by XCD locality (r10); vmcnt waits are
// per-wave -- wait must precede a barrier (r12); count LDS bytes per phase,
// not just HBM bytes (r13).
//
// Pipeline:
//   0. prep: h->hb (bf16), Wq|Wk|Wv->wcat (bf16)
//   1. QKVb = hb @ wcat^T        (4096x3072 bf16)            [MFMA GEMM 256^2]
//   2. Spart[bh,c] = K^T V partial over 128 rows             [VALU]
//   2b. S = sum_c Spart          (each line read once)       [BW]
//   3. Tt[b][n,k] = (S_h Wo_h^T)^T  (2 x 1024x1024 bf16)     [VALU]
//   4. out = Q @ Tt_b^T          (4096x1024 fp32 -> d_out)   [MFMA GEMM]

typedef unsigned short u16;
typedef unsigned int u32;
typedef __attribute__((ext_vector_type(8))) short bf16x8;
typedef __attribute__((ext_vector_type(4))) float f32x4;

__device__ __forceinline__ void async_copy16(void* lds, const void* g) {
  __builtin_amdgcn_global_load_lds((const __attribute__((address_space(1))) void*)g,
                                   (__attribute__((address_space(3))) void*)lds,
                                   16, 0, 0);
}

__device__ __forceinline__ u16 f2bf(float f) {
  union { __hip_bfloat16 h; u16 u; } c;
  c.h = __float2bfloat16(f);
  return c.u;
}
__device__ __forceinline__ float bflo(u32 w) {
  union { u32 u; float f; } c; c.u = w << 16; return c.f;
}
__device__ __forceinline__ float bfhi(u32 w) {
  union { u32 u; float f; } c; c.u = w & 0xFFFF0000u; return c.f;
}
__device__ __forceinline__ ushort4 cvt4(float4 v) {
  ushort4 o; o.x = f2bf(v.x); o.y = f2bf(v.y); o.z = f2bf(v.z); o.w = f2bf(v.w);
  return o;
}

// ---------------------------------------------------------------- prep ------
__global__ __launch_bounds__(256) void prep(const float4* __restrict__ h,
                                            const float4* __restrict__ wq,
                                            const float4* __restrict__ wk,
                                            const float4* __restrict__ wv,
                                            ushort4* __restrict__ hb,
                                            ushort4* __restrict__ wcat) {
  int i = blockIdx.x * 256 + threadIdx.x;  // float4 units
  if (i < 1048576) { hb[i] = cvt4(h[i]); return; }          // h: 4096x1024
  i -= 1048576;
  if (i < 262144) { wcat[i] = cvt4(wq[i]); return; }
  i -= 262144;
  if (i < 262144) { wcat[262144 + i] = cvt4(wk[i]); return; }
  i -= 262144;
  wcat[524288 + i] = cvt4(wv[i]);
}

// ---------------------------------------- 256^2 BK=32 4-buffer NT GEMM ------
// C[m,n] = sum_k A[m*1024+k] * B[n*1024+k], M=4096, N=3072, K=1024, bf16 out.
// 512 threads = 8 waves (2 Mhalves x 4 Ncols), per-wave C = 128x64.

#define VW(N) asm volatile("s_waitcnt vmcnt(" #N ")" ::: "memory")
#define NOPW ((void)0)

// one phase = one K-tile (BK=32): reads | stage | lgkm | MFMA | VWAIT | barrier
#define PHASE(KT, DO_STAGE, VWAIT)                                           \
  do {                                                                       \
    const u16* Ab = &Als[(KT) & 3][wm * 32 + aoff];                          \
    const u16* Bb = &Bls[(KT) & 3][wn * 32 + aoff];                          \
    bf16x8 af[8], bv[4];                                                     \
    _Pragma("unroll") for (int i = 0; i < 8; ++i)                            \
        af[i] = *(const bf16x8*)(Ab + i * 512);                              \
    _Pragma("unroll") for (int j = 0; j < 4; ++j)                            \
        bv[j] = *(const bf16x8*)(Bb + j * 512);                              \
    DO_STAGE;                                                                \
    asm volatile("s_waitcnt lgkmcnt(0)" ::: "memory");                       \
    __builtin_amdgcn_sched_barrier(0);                                       \
    __builtin_amdgcn_s_setprio(1);                                           \
    _Pragma("unroll") for (int i = 0; i < 8; ++i)                            \
        _Pragma("unroll") for (int j = 0; j < 4; ++j)                        \
            acc[i][j] = __builtin_amdgcn_mfma_f32_16x16x32_bf16(             \
                af[i], bv[j], acc[i][j], 0, 0, 0);                           \
    __builtin_amdgcn_s_setprio(0);                                           \
    VWAIT;                                                                   \
    __builtin_amdgcn_s_barrier();                                            \
  } while (0)

__global__ __launch_bounds__(512, 2) void gemm256(const u16* __restrict__ A,
                                                  const u16* __restrict__ B,
                                                  u16* __restrict__ C) {
  __shared__ u16 Als[4][8192];   // [buf][256 rows][32 k]  (16 KiB each)
  __shared__ u16 Bls[4][8192];
  const int t = threadIdx.x;
  const int lane = t & 63;
  const int wave = t >> 6;                 // 0..7
  const int wm = (wave >> 2) * 128;        // 0 / 128
  const int wn = (wave & 3) * 64;          // 0,64,128,192
  const int lrow = lane & 15;
  const int quad = lane >> 4;

  // bijective XCD swizzle (192 blocks, 192%8==0): XCD x -> m-panels {2x,2x+1}
  const int bid = blockIdx.x;
  const int xcd = bid & 7;
  const int c8 = bid >> 3;                 // 0..23
  const int m0 = (xcd * 2 + (c8 >= 12 ? 1 : 0)) * 256;
  const int n0 = (c8 >= 12 ? c8 - 12 : c8) * 256;

  // staging: one inst = 16 rows x 32 k = 1 KB; lane l -> row +(l>>2),
  // LDS slot l&3 holding global granule (l&3)^((l>>3)&3)  (linear dest).
  const int srow = lane >> 2;                       // 0..15
  const int sgk  = (lane & 3) ^ ((lane >> 3) & 3);  // global k-granule
  const u16* Ag = A + (size_t)(m0 + 32 * wave + srow) * 1024 + sgk * 8;
  const u16* Bg = B + (size_t)(n0 + 32 * wave + srow) * 1024 + sgk * 8;

  // read swizzle: slot holding global granule quad at row r is quad^((r>>1)&3);
  // r = wm|wn + i*16 + lrow  ->  (r>>1)&3 == (lrow>>1)&3 (bases are mult of 16)
  const int swz = (lrow >> 1) & 3;
  const int aoff = lrow * 32 + ((quad ^ swz) << 3);  // u16 units

  f32x4 acc[8][4];
#pragma unroll
  for (int i = 0; i < 8; ++i)
#pragma unroll
    for (int j = 0; j < 4; ++j) acc[i][j] = {0.f, 0.f, 0.f, 0.f};

  // stage tile kt (A and B, 4 insts/thread) into buf kt&3
  auto stage = [&](int kt) {
    const int buf = kt & 3;
#pragma unroll
    for (int j = 0; j < 2; ++j) {
      const int rb = (32 * wave + 16 * j) * 32;      // region base (u16)
      async_copy16(&Als[buf][rb + lane * 8],
                   Ag + (size_t)(16 * j) * 1024 + kt * 32);
      async_copy16(&Bls[buf][rb + lane * 8],
                   Bg + (size_t)(16 * j) * 1024 + kt * 32);
    }
  };

  // prologue: stage tiles 0,1,2 (12 insts); wait tile0 (oldest 4); barrier.
  stage(0); stage(1); stage(2);
  VW(8);
  __builtin_amdgcn_s_barrier();

  // steady state: phase kt stages kt+3 (4 insts; 12 in flight), VW(8)
  // drains exactly tile kt+1 before the barrier releasing phase kt+1.
#pragma unroll 1
  for (int kt = 0; kt < 29; ++kt) {
    PHASE(kt, stage(kt + 3), VW(8));
  }
  PHASE(29, NOPW, VW(4));   // in flight: t30,t31 -> drain t30
  PHASE(30, NOPW, VW(0));   // drain t31
  PHASE(31, NOPW, NOPW);

  // C/D layout (verified m89/m91): col = lane&15, row = (lane>>4)*4 + r
  const int crow0 = m0 + wm + quad * 4;
  const int ccol0 = n0 + wn + lrow;
#pragma unroll
  for (int mf = 0; mf < 8; ++mf)
#pragma unroll
    for (int nf = 0; nf < 4; ++nf)
#pragma unroll
      for (int r = 0; r < 4; ++r)
        C[(size_t)(crow0 + mf * 16 + r) * 3072 + ccol0 + nf * 16] =
            f2bf(acc[mf][nf][r]);
}

// ------------------------------------------------------------- NT GEMM ------
// (kept for gemm2)  C[m,n] = sum_k A[m*lda+k] * B[n*K+k].
template <bool BF16_OUT, int BM, int BN>
__global__ __launch_bounds__(256) void gemm_bt(const u16* __restrict__ A, int lda,
                                               const u16* __restrict__ B0,
                                               const u16* __restrict__ B1,
                                               void* __restrict__ Cv,
                                               int N, int K) {
  constexpr int WR = BM / 64;       // wave rows (2 or 1)
  constexpr int WC = 4 / WR;        // wave cols (2 or 4)
  constexpr int NI = BN / WC / 16;  // 16-col MFMA tiles per wave
  __shared__ u16 Als[BM * 64];
  __shared__ u16 Bls[BN * 64];
  const int t = threadIdx.x;
  const int lane = t & 63;
  const int wave = t >> 6;
  const int wm = (wave / WC) * 64;
  const int wn = (wave % WC) * (BN / WC);
  const int lrow = lane & 15;      // MFMA m/n index
  const int quad = lane >> 4;      // MFMA k-group (16-B units)
  const int m0 = blockIdx.y * BM;
  const int n0 = blockIdx.x * BN;
  const u16* B = (B1 != nullptr && m0 >= 2048) ? B1 : B0;

  const int srow = t >> 3;
  const int scol = (((t & 7) ^ (srow & 7)) * 8);
  const u16* Ag0 = A + (size_t)(m0 + srow) * lda + scol;
  const u16* Bg0 = B + (size_t)(n0 + srow) * K + scol;
  u16* Al0 = Als + t * 8;  // + c*2048 u16 per copy (32 rows)
  u16* Bl0 = Bls + t * 8;

  f32x4 acc[4][NI];
#pragma unroll
  for (int i = 0; i < 4; ++i)
#pragma unroll
    for (int j = 0; j < NI; ++j) acc[i][j] = {0.f, 0.f, 0.f, 0.f};

  for (int k0 = 0; k0 < K; k0 += 64) {
#pragma unroll
    for (int c = 0; c < BM / 32; ++c)
      async_copy16(Al0 + c * 2048, Ag0 + (size_t)(c * 32) * lda + k0);
#pragma unroll
    for (int c = 0; c < BN / 32; ++c)
      async_copy16(Bl0 + c * 2048, Bg0 + (size_t)(c * 32) * K + k0);
    __syncthreads();

#pragma unroll
    for (int half = 0; half < 2; ++half) {
      const int gg = quad + half * 4;  // global k-group within BK=64
      bf16x8 af[4], bfv[NI];
#pragma unroll
      for (int i = 0; i < 4; ++i) {
        const int ra = wm + i * 16 + lrow;
        af[i] = *(const bf16x8*)(Als + ra * 64 + ((gg ^ (ra & 7)) << 3));
      }
#pragma unroll
      for (int i = 0; i < NI; ++i) {
        const int rb = wn + i * 16 + lrow;
        bfv[i] = *(const bf16x8*)(Bls + rb * 64 + ((gg ^ (rb & 7)) << 3));
      }
#pragma unroll
      for (int mi = 0; mi < 4; ++mi)
#pragma unroll
        for (int ni = 0; ni < NI; ++ni)
          acc[mi][ni] = __builtin_amdgcn_mfma_f32_16x16x32_bf16(
              af[mi], bfv[ni], acc[mi][ni], 0, 0, 0);
    }
    __syncthreads();
  }

  const int crow0 = m0 + wm + (lane >> 4) * 4;
  const int ccol0 = n0 + wn + (lane & 15);
#pragma unroll
  for (int mi = 0; mi < 4; ++mi)
#pragma unroll
    for (int ni = 0; ni < NI; ++ni) {
      const int col = ccol0 + ni * 16;
#pragma unroll
      for (int r = 0; r < 4; ++r) {
        const size_t idx = (size_t)(crow0 + mi * 16 + r) * N + col;
        if (BF16_OUT) ((u16*)Cv)[idx]   = f2bf(acc[mi][ni][r]);
        else          ((float*)Cv)[idx] = acc[mi][ni][r];
      }
    }
}

// --------------------------------------------- Spart = partial K^T V --------
__global__ __launch_bounds__(256) void s_kernel(const u16* __restrict__ QKV,
                                                float* __restrict__ Spart) {
  const int bh = blockIdx.x;
  const int b = bh >> 4, hh = bh & 15;
  const int row0 = b * 2048 + blockIdx.y * 128;
  const u16* Kg = QKV + (size_t)row0 * 3072 + 1024 + hh * 64;

  __shared__ float Ks[64][64];
  __shared__ float Vs[64][64];
  const int t = threadIdx.x;
  const int lr = t >> 2;        // 0..63 row within stage
  const int lc = (t & 3) * 16;  // col group (16 cols)
  const int d1 = (t >> 4) * 4;
  const int d2 = (t & 15) * 4;

  float acc[4][4] = {};

  for (int r0 = 0; r0 < 128; r0 += 64) {
    const u16* kp = Kg + (size_t)(r0 + lr) * 3072 + lc;
    const uint4 kw0 = *(const uint4*)kp;
    const uint4 kw1 = *(const uint4*)(kp + 8);
    const uint4 vw0 = *(const uint4*)(kp + 1024);  // V = K + 1024 cols
    const uint4 vw1 = *(const uint4*)(kp + 1032);
    __syncthreads();  // prev-iter readers done
    float* kd = &Ks[lr][lc];
    *(float4*)(kd)      = float4{bflo(kw0.x), bfhi(kw0.x), bflo(kw0.y), bfhi(kw0.y)};
    *(float4*)(kd + 4)  = float4{bflo(kw0.z), bfhi(kw0.z), bflo(kw0.w), bfhi(kw0.w)};
    *(float4*)(kd + 8)  = float4{bflo(kw1.x), bfhi(kw1.x), bflo(kw1.y), bfhi(kw1.y)};
    *(float4*)(kd + 12) = float4{bflo(kw1.z), bfhi(kw1.z), bflo(kw1.w), bfhi(kw1.w)};
    float* vd = &Vs[lr][lc];
    *(float4*)(vd)      = float4{bflo(vw0.x), bfhi(vw0.x), bflo(vw0.y), bfhi(vw0.y)};
    *(float4*)(vd + 4)  = float4{bflo(vw0.z), bfhi(vw0.z), bflo(vw0.w), bfhi(vw0.w)};
    *(float4*)(vd + 8)  = float4{bflo(vw1.x), bfhi(vw1.x), bflo(vw1.y), bfhi(vw1.y)};
    *(float4*)(vd + 12) = float4{bflo(vw1.z), bfhi(vw1.z), bflo(vw1.w), bfhi(vw1.w)};
    __syncthreads();
#pragma unroll
    for (int r = 0; r < 64; ++r) {
      float kv[4], vv[4];
      *(float4*)kv = *(const float4*)&Ks[r][d1];
      *(float4*)vv = *(const float4*)&Vs[r][d2];
#pragma unroll
      for (int i = 0; i < 4; ++i)
#pragma unroll
        for (int j = 0; j < 4; ++j) acc[i][j] += kv[i] * vv[j];
    }
  }
  float* Sp = Spart + ((size_t)bh * 16 + blockIdx.y) * 4096;
#pragma unroll
  for (int i = 0; i < 4; ++i)
    *(float4*)&Sp[(d1 + i) * 64 + d2] =
        float4{acc[i][0], acc[i][1], acc[i][2], acc[i][3]};
}

// ---------------------------------------------------- S = sum_c Spart -------
__global__ __launch_bounds__(256) void reduce_s(const float4* __restrict__ Spart,
                                                float4* __restrict__ S) {
  const int g = blockIdx.x * 256 + threadIdx.x;  // 0..32767
  const int bh = g >> 10, j = g & 1023;
  const float4* p = Spart + (size_t)bh * 16384 + j;  // 16 chunks * 1024 f4
  float4 a = {0.f, 0.f, 0.f, 0.f};
#pragma unroll
  for (int c = 0; c < 16; ++c) {
    const float4 v = p[(size_t)c * 1024];
    a.x += v.x; a.y += v.y; a.z += v.z; a.w += v.w;
  }
  S[g] = a;
}

// ------------------------------------------- Tt = (S_h Wo_h^T)^T ------------
__global__ __launch_bounds__(256) void t_kernel(const float* __restrict__ S,
                                                const float* __restrict__ Wo,
                                                u16* __restrict__ Tt) {
  const int n0 = blockIdx.x * 128;
  const int hh = blockIdx.y;
  const int b  = blockIdx.z;
  __shared__ float Ss[64][68];
  __shared__ float Ws[128][68];
  const int t = threadIdx.x;
  {
    const float* sg = S + (size_t)(b * 16 + hh) * 4096 + (t >> 2) * 64 + (t & 3) * 16;
    float* sd = &Ss[t >> 2][(t & 3) * 16];
#pragma unroll
    for (int i = 0; i < 4; ++i) *(float4*)(sd + 4 * i) = *(const float4*)(sg + 4 * i);
    const float* wg = Wo + (size_t)(n0 + (t >> 1)) * 1024 + hh * 64 + (t & 1) * 32;
    float* wd = &Ws[t >> 1][(t & 1) * 32];
#pragma unroll
    for (int i = 0; i < 8; ++i) *(float4*)(wd + 4 * i) = *(const float4*)(wg + 4 * i);
  }
  __syncthreads();

  const int td = (t >> 4) * 4;  // d = td..td+3
  const int tn = t & 15;        // n = n0 + tn + 16k
  float acc[4][8] = {};
  for (int jj = 0; jj < 64; jj += 4) {
    float4 sv[4], wv[8];
#pragma unroll
    for (int i = 0; i < 4; ++i) sv[i] = *(const float4*)&Ss[td + i][jj];
#pragma unroll
    for (int k = 0; k < 8; ++k) wv[k] = *(const float4*)&Ws[tn + 16 * k][jj];
#pragma unroll
    for (int i = 0; i < 4; ++i)
#pragma unroll
      for (int k = 0; k < 8; ++k)
        acc[i][k] += sv[i].x * wv[k].x + sv[i].y * wv[k].y +
                     sv[i].z * wv[k].z + sv[i].w * wv[k].w;
  }

  u16* tp = Tt + (size_t)b * 1048576;
#pragma unroll
  for (int k = 0; k < 8; ++k) {
    const int n = n0 + tn + 16 * k;
    ushort4 o;
    o.x = f2bf(acc[0][k]); o.y = f2bf(acc[1][k]);
    o.z = f2bf(acc[2][k]); o.w = f2bf(acc[3][k]);
    *(ushort4*)&tp[(size_t)n * 1024 + hh * 64 + td] = o;
  }
}

// ---------------------------------------------------------------------------
extern "C" void kernel_launch(void* const* d_in, const int* in_sizes, int n_in,
                              void* d_out, int out_size, void* d_ws, size_t ws_size,
                              hipStream_t stream) {
  const float* h  = (const float*)d_in[0];  // (4096, 1024) fp32
  // d_in[1] = key_pe: dead branch in reference, unused.
  const float* Wq = (const float*)d_in[2];
  const float* Wk = (const float*)d_in[3];
  const float* Wv = (const float*)d_in[4];
  const float* Wo = (const float*)d_in[5];

  char* ws = (char*)d_ws;
  u16*   hb    = (u16*)(ws);                    // 4096*1024*2 = 8 MiB @ 0
  u16*   wcat  = (u16*)(ws + (8ull  << 20));    // 3072*1024*2 = 6 MiB
  u16*   QKVb  = (u16*)(ws + (16ull << 20));    // 4096*3072*2 = 24 MiB
  float* S     = (float*)(ws + (40ull << 20));  // 32*64*64*4  = 0.5 MiB
  u16*   Tt    = (u16*)(ws + (41ull << 20));    // 2*1024*1024*2 = 4 MiB
  float* Spart = (float*)(ws + (48ull << 20));  // 512*64*64*4 = 8 MiB
  // total ws use: 56 MiB (ws_size = 256 MiB)

  prep<<<7168, 256, 0, stream>>>((const float4*)h, (const float4*)Wq,
                                 (const float4*)Wk, (const float4*)Wv,
                                 (ushort4*)hb, (ushort4*)wcat);
  // QKVb = hb @ wcat^T : (4096 x 3072), K=1024, 192 blocks (1/CU, 8 waves)
  gemm256<<<192, 512, 0, stream>>>(hb, wcat, QKVb);
  s_kernel<<<dim3(32, 16), 256, 0, stream>>>(QKVb, Spart);
  reduce_s<<<128, 256, 0, stream>>>((const float4*)Spart, (float4*)S);
  t_kernel<<<dim3(8, 16, 2), 256, 0, stream>>>(S, Wo, Tt);
  // out = Q @ Tt_b^T : (4096 x 1024), K=1024, BM=64 -> 512 blocks = 2/CU
  gemm_bt<false, 64, 128><<<dim3(8, 64), 256, 0, stream>>>(
      QKVb, 3072, Tt, Tt + 1048576, d_out, 1024, 1024);
}

// Round 4
// 151.480 us; speedup vs baseline: 1.1324x; 1.0370x over previous
//
#include <hip/hip_runtime.h>
#include <hip/hip_bf16.h>

// B=2, M=2048, HID=1024, NH=16, D=64.  No softmax in the reference, so
//   out = ((h Wq^T)(h Wk^T)^T (h Wv^T)) Wo^T
// reassociates twice:  S_{b,h} = K_h^T V_h  (64x64), and
//   out_b = Q_b @ T_b   with  T_b[h*64+d, n] = sum_j S_{b,h}[d,j] Wo[n, h*64+j]
//
// Dtypes: inputs fp32, d_out fp32; internal bf16 with fp32 accumulate.
//
// Round-15: r14's BK=32 4-buffer 1-phase-per-K-tile schedule verified good
// (absmax 4, gemm1 50->37us) but geometry was wrong twice over: 256^2 tile
// -> 192 blocks = 75% of CUs, and wave-tile 128x64 re-broadcast A to all
// waves.  r15 keeps the EXACT schedule (stage kt+3 into buf (kt+3)&3, VW(2V)
// steady / VW(V),VW(0) tail, lgkmcnt(0) before the single per-phase barrier)
// and re-instantiates it as one template used by BOTH big GEMMs:
//   gemm1: 128x384 tile, grid 32x8=256 blocks (100% CUs), waves 2x4 ->
//          wave-tile 64x96 (MI=4,NI=6), V=4: VW(8)/VW(4)/VW(0).
//   gemm2: 128x128 tile, grid 32x8=256 blocks, wave-tile 64x32 (MI=4,NI=2),
//          V=2: VW(4)/VW(2)/VW(0); replaces the 2-barrier gemm_bt.
// Staging is uniform per thread (V = (BM+BN)/128 insts), so the per-wave
// vmcnt ledger is exact for every wave.  Row bases stay multiples of 16 so
// the r14 store/read swizzle identity ((row>>1)&3) is unchanged.
// Lessons kept: no dense-reduction atomics (r6->r7); never trade
// high-occupancy FLOPs for low-occupancy FLOPs (r8); price redundant
// re-reads by XCD locality (r10); vmcnt waits are per-wave -- wait must
// precede a barrier (r12); count LDS bytes per phase (r13); grid must cover
// all 256 CUs (r14).
//
// Pipeline:
//   0. prep: h->hb (bf16), Wq|Wk|Wv->wcat (bf16)
//   1. QKVb = hb @ wcat^T        (4096x3072 bf16)            [gemm32<384>]
//   2. Spart[bh,c] = K^T V partial over 128 rows             [VALU]
//   2b. S = sum_c Spart          (each line read once)       [BW]
//   3. Tt[b][n,k] = (S_h Wo_h^T)^T  (2 x 1024x1024 bf16)     [VALU]
//   4. out = Q @ Tt_b^T          (4096x1024 fp32 -> d_out)   [gemm32<128>]

typedef unsigned short u16;
typedef unsigned int u32;
typedef __attribute__((ext_vector_type(8))) short bf16x8;
typedef __attribute__((ext_vector_type(4))) float f32x4;

__device__ __forceinline__ void async_copy16(void* lds, const void* g) {
  __builtin_amdgcn_global_load_lds((const __attribute__((address_space(1))) void*)g,
                                   (__attribute__((address_space(3))) void*)lds,
                                   16, 0, 0);
}

__device__ __forceinline__ u16 f2bf(float f) {
  union { __hip_bfloat16 h; u16 u; } c;
  c.h = __float2bfloat16(f);
  return c.u;
}
__device__ __forceinline__ float bflo(u32 w) {
  union { u32 u; float f; } c; c.u = w << 16; return c.f;
}
__device__ __forceinline__ float bfhi(u32 w) {
  union { u32 u; float f; } c; c.u = w & 0xFFFF0000u; return c.f;
}
__device__ __forceinline__ ushort4 cvt4(float4 v) {
  ushort4 o; o.x = f2bf(v.x); o.y = f2bf(v.y); o.z = f2bf(v.z); o.w = f2bf(v.w);
  return o;
}

template <int N> __device__ __forceinline__ void vw() {
  if constexpr (N == 8)      asm volatile("s_waitcnt vmcnt(8)" ::: "memory");
  else if constexpr (N == 4) asm volatile("s_waitcnt vmcnt(4)" ::: "memory");
  else if constexpr (N == 2) asm volatile("s_waitcnt vmcnt(2)" ::: "memory");
  else if constexpr (N == 0) asm volatile("s_waitcnt vmcnt(0)" ::: "memory");
}

// ---------------------------------------------------------------- prep ------
__global__ __launch_bounds__(256) void prep(const float4* __restrict__ h,
                                            const float4* __restrict__ wq,
                                            const float4* __restrict__ wk,
                                            const float4* __restrict__ wv,
                                            ushort4* __restrict__ hb,
                                            ushort4* __restrict__ wcat) {
  int i = blockIdx.x * 256 + threadIdx.x;  // float4 units
  if (i < 1048576) { hb[i] = cvt4(h[i]); return; }          // h: 4096x1024
  i -= 1048576;
  if (i < 262144) { wcat[i] = cvt4(wq[i]); return; }
  i -= 262144;
  if (i < 262144) { wcat[262144 + i] = cvt4(wk[i]); return; }
  i -= 262144;
  wcat[524288 + i] = cvt4(wv[i]);
}

// ------------------------------ BK=32 4-buffer counted-vmcnt NT GEMM --------
// C[m,n] = sum_k A[m*lda+k] * B[n*1024+k], M=4096, K=1024.  BM=128 fixed.
// grid 256 = 32 m-tiles x 8 n-tiles (XCD-swizzled), 512 thr = 8 waves (2x4).
// One phase per K-tile: {MI+NI ds_read_b128 | stage tile kt+3 | lgkmcnt(0) |
// MI*NI MFMA (setprio) | vmcnt(2V) | s_barrier}.
// Safety (r14-verified): read buf kt&3 vs stage buf (kt+3)&3 always
// distinct; per-wave lgkmcnt(0) precedes the phase barrier (WAR-safe);
// tile kt+1 gated by all waves' vmcnt+barrier at end of phase kt.

#define NOPW ((void)0)

#define PHASE(KT, DO_STAGE, VWAIT)                                           \
  do {                                                                       \
    const u16* Ab = &Als[(KT) & 3][wm * 32 + aoff];                          \
    const u16* Bb = &Bls[(KT) & 3][wn * 32 + aoff];                          \
    bf16x8 af[MI], bv[NI];                                                   \
    _Pragma("unroll") for (int i = 0; i < MI; ++i)                           \
        af[i] = *(const bf16x8*)(Ab + i * 512);                              \
    _Pragma("unroll") for (int j = 0; j < NI; ++j)                           \
        bv[j] = *(const bf16x8*)(Bb + j * 512);                              \
    DO_STAGE;                                                                \
    asm volatile("s_waitcnt lgkmcnt(0)" ::: "memory");                       \
    __builtin_amdgcn_sched_barrier(0);                                       \
    __builtin_amdgcn_s_setprio(1);                                           \
    _Pragma("unroll") for (int i = 0; i < MI; ++i)                           \
        _Pragma("unroll") for (int j = 0; j < NI; ++j)                       \
            acc[i][j] = __builtin_amdgcn_mfma_f32_16x16x32_bf16(             \
                af[i], bv[j], acc[i][j], 0, 0, 0);                           \
    __builtin_amdgcn_s_setprio(0);                                           \
    VWAIT;                                                                   \
    __builtin_amdgcn_s_barrier();                                            \
  } while (0)

template <bool BF16_OUT, int BN>
__global__ __launch_bounds__(512, 2) void gemm32(const u16* __restrict__ A,
                                                 int lda,
                                                 const u16* __restrict__ B0,
                                                 const u16* __restrict__ B1,
                                                 void* __restrict__ Cv,
                                                 int N) {
  constexpr int SA = 1;              // A staging insts/thread (BM=128)
  constexpr int SB = BN / 128;       // B staging insts/thread
  constexpr int V  = SA + SB;        // insts/thread per tile
  constexpr int MI = 4;              // 64-row wave half -> 4 m-frags
  constexpr int NI = BN / 4 / 16;    // wave covers BN/4 cols

  __shared__ u16 Als[4][128 * 32];
  __shared__ u16 Bls[4][BN * 32];
  const int t = threadIdx.x;
  const int lane = t & 63;
  const int wave = t >> 6;                 // 0..7
  const int wm = (wave >> 2) * 64;         // 0 / 64
  const int wn = (wave & 3) * (BN / 4);    // mult of 16
  const int lrow = lane & 15;
  const int quad = lane >> 4;

  // bijective XCD swizzle (256 blocks): XCD x -> m-tiles {4x..4x+3} x all 8 n
  const int bid = blockIdx.x;
  const int xcd = bid & 7;
  const int c = bid >> 3;                  // 0..31
  const int m0 = (xcd * 4 + (c >> 3)) * 128;
  const int n0 = (c & 7) * BN;
  const u16* B = (B1 != nullptr && m0 >= 2048) ? B1 : B0;

  // staging: one inst = 16 rows x 32 k = 1 KB; lane l -> row +(l>>2),
  // LDS slot l&3 holding global k-granule (l&3)^((l>>3)&3)  (linear dest).
  const int srow = lane >> 2;                       // 0..15
  const int sgk  = (lane & 3) ^ ((lane >> 3) & 3);  // global k-granule
  const u16* Ag = A + (size_t)(m0 + wave * (SA * 16) + srow) * lda + sgk * 8;
  const u16* Bg = B + (size_t)(n0 + wave * (SB * 16) + srow) * 1024 + sgk * 8;

  // read swizzle: slot holding granule `quad` at row r is quad^((r>>1)&3);
  // all row bases are multiples of 16, so (r>>1)&3 == (lrow>>1)&3.
  const int swz = (lrow >> 1) & 3;
  const int aoff = lrow * 32 + ((quad ^ swz) << 3);  // u16 units

  f32x4 acc[MI][NI];
#pragma unroll
  for (int i = 0; i < MI; ++i)
#pragma unroll
    for (int j = 0; j < NI; ++j) acc[i][j] = {0.f, 0.f, 0.f, 0.f};

  // stage tile kt (V insts/thread: SA for A, SB for B) into buf kt&3
  auto stage = [&](int kt) {
    const int buf = kt & 3;
#pragma unroll
    for (int j = 0; j < SA; ++j) {
      const int ch = wave * SA + j;                  // 16-row chunk index
      async_copy16(&Als[buf][ch * 512 + lane * 8],
                   Ag + (size_t)(j * 16) * lda + kt * 32);
    }
#pragma unroll
    for (int j = 0; j < SB; ++j) {
      const int ch = wave * SB + j;
      async_copy16(&Bls[buf][ch * 512 + lane * 8],
                   Bg + (size_t)(j * 16) * 1024 + kt * 32);
    }
  };

  // prologue: stage tiles 0,1,2 (3V insts); wait tile0 (<=2V left); barrier.
  stage(0); stage(1); stage(2);
  vw<2 * V>();
  __builtin_amdgcn_s_barrier();

  // steady: phase kt stages kt+3 (3V in flight), vw<2V> drains tile kt+1.
#pragma unroll 1
  for (int kt = 0; kt < 29; ++kt) {
    PHASE(kt, stage(kt + 3), vw<2 * V>());
  }
  PHASE(29, NOPW, vw<V>());   // in flight: t30,t31 -> drain t30
  PHASE(30, NOPW, vw<0>());   // drain t31
  PHASE(31, NOPW, NOPW);

  // C/D layout (verified m89/m91): col = lane&15, row = (lane>>4)*4 + r
  const int crow0 = m0 + wm + quad * 4;
  const int ccol0 = n0 + wn + lrow;
#pragma unroll
  for (int mf = 0; mf < MI; ++mf)
#pragma unroll
    for (int nf = 0; nf < NI; ++nf)
#pragma unroll
      for (int r = 0; r < 4; ++r) {
        const size_t idx = (size_t)(crow0 + mf * 16 + r) * N + ccol0 + nf * 16;
        if (BF16_OUT) ((u16*)Cv)[idx]   = f2bf(acc[mf][nf][r]);
        else          ((float*)Cv)[idx] = acc[mf][nf][r];
      }
}

// --------------------------------------------- Spart = partial K^T V --------
__global__ __launch_bounds__(256) void s_kernel(const u16* __restrict__ QKV,
                                                float* __restrict__ Spart) {
  const int bh = blockIdx.x;
  const int b = bh >> 4, hh = bh & 15;
  const int row0 = b * 2048 + blockIdx.y * 128;
  const u16* Kg = QKV + (size_t)row0 * 3072 + 1024 + hh * 64;

  __shared__ float Ks[64][64];
  __shared__ float Vs[64][64];
  const int t = threadIdx.x;
  const int lr = t >> 2;        // 0..63 row within stage
  const int lc = (t & 3) * 16;  // col group (16 cols)
  const int d1 = (t >> 4) * 4;
  const int d2 = (t & 15) * 4;

  float acc[4][4] = {};

  for (int r0 = 0; r0 < 128; r0 += 64) {
    const u16* kp = Kg + (size_t)(r0 + lr) * 3072 + lc;
    const uint4 kw0 = *(const uint4*)kp;
    const uint4 kw1 = *(const uint4*)(kp + 8);
    const uint4 vw0 = *(const uint4*)(kp + 1024);  // V = K + 1024 cols
    const uint4 vw1 = *(const uint4*)(kp + 1032);
    __syncthreads();  // prev-iter readers done
    float* kd = &Ks[lr][lc];
    *(float4*)(kd)      = float4{bflo(kw0.x), bfhi(kw0.x), bflo(kw0.y), bfhi(kw0.y)};
    *(float4*)(kd + 4)  = float4{bflo(kw0.z), bfhi(kw0.z), bflo(kw0.w), bfhi(kw0.w)};
    *(float4*)(kd + 8)  = float4{bflo(kw1.x), bfhi(kw1.x), bflo(kw1.y), bfhi(kw1.y)};
    *(float4*)(kd + 12) = float4{bflo(kw1.z), bfhi(kw1.z), bflo(kw1.w), bfhi(kw1.w)};
    float* vd = &Vs[lr][lc];
    *(float4*)(vd)      = float4{bflo(vw0.x), bfhi(vw0.x), bflo(vw0.y), bfhi(vw0.y)};
    *(float4*)(vd + 4)  = float4{bflo(vw0.z), bfhi(vw0.z), bflo(vw0.w), bfhi(vw0.w)};
    *(float4*)(vd + 8)  = float4{bflo(vw1.x), bfhi(vw1.x), bflo(vw1.y), bfhi(vw1.y)};
    *(float4*)(vd + 12) = float4{bflo(vw1.z), bfhi(vw1.z), bflo(vw1.w), bfhi(vw1.w)};
    __syncthreads();
#pragma unroll
    for (int r = 0; r < 64; ++r) {
      float kv[4], vv[4];
      *(float4*)kv = *(const float4*)&Ks[r][d1];
      *(float4*)vv = *(const float4*)&Vs[r][d2];
#pragma unroll
      for (int i = 0; i < 4; ++i)
#pragma unroll
        for (int j = 0; j < 4; ++j) acc[i][j] += kv[i] * vv[j];
    }
  }
  float* Sp = Spart + ((size_t)bh * 16 + blockIdx.y) * 4096;
#pragma unroll
  for (int i = 0; i < 4; ++i)
    *(float4*)&Sp[(d1 + i) * 64 + d2] =
        float4{acc[i][0], acc[i][1], acc[i][2], acc[i][3]};
}

// ---------------------------------------------------- S = sum_c Spart -------
__global__ __launch_bounds__(256) void reduce_s(const float4* __restrict__ Spart,
                                                float4* __restrict__ S) {
  const int g = blockIdx.x * 256 + threadIdx.x;  // 0..32767
  const int bh = g >> 10, j = g & 1023;
  const float4* p = Spart + (size_t)bh * 16384 + j;  // 16 chunks * 1024 f4
  float4 a = {0.f, 0.f, 0.f, 0.f};
#pragma unroll
  for (int c = 0; c < 16; ++c) {
    const float4 v = p[(size_t)c * 1024];
    a.x += v.x; a.y += v.y; a.z += v.z; a.w += v.w;
  }
  S[g] = a;
}

// ------------------------------------------- Tt = (S_h Wo_h^T)^T ------------
__global__ __launch_bounds__(256) void t_kernel(const float* __restrict__ S,
                                                const float* __restrict__ Wo,
                                                u16* __restrict__ Tt) {
  const int n0 = blockIdx.x * 128;
  const int hh = blockIdx.y;
  const int b  = blockIdx.z;
  __shared__ float Ss[64][68];
  __shared__ float Ws[128][68];
  const int t = threadIdx.x;
  {
    const float* sg = S + (size_t)(b * 16 + hh) * 4096 + (t >> 2) * 64 + (t & 3) * 16;
    float* sd = &Ss[t >> 2][(t & 3) * 16];
#pragma unroll
    for (int i = 0; i < 4; ++i) *(float4*)(sd + 4 * i) = *(const float4*)(sg + 4 * i);
    const float* wg = Wo + (size_t)(n0 + (t >> 1)) * 1024 + hh * 64 + (t & 1) * 32;
    float* wd = &Ws[t >> 1][(t & 1) * 32];
#pragma unroll
    for (int i = 0; i < 8; ++i) *(float4*)(wd + 4 * i) = *(const float4*)(wg + 4 * i);
  }
  __syncthreads();

  const int td = (t >> 4) * 4;  // d = td..td+3
  const int tn = t & 15;        // n = n0 + tn + 16k
  float acc[4][8] = {};
  for (int jj = 0; jj < 64; jj += 4) {
    float4 sv[4], wv[8];
#pragma unroll
    for (int i = 0; i < 4; ++i) sv[i] = *(const float4*)&Ss[td + i][jj];
#pragma unroll
    for (int k = 0; k < 8; ++k) wv[k] = *(const float4*)&Ws[tn + 16 * k][jj];
#pragma unroll
    for (int i = 0; i < 4; ++i)
#pragma unroll
      for (int k = 0; k < 8; ++k)
        acc[i][k] += sv[i].x * wv[k].x + sv[i].y * wv[k].y +
                     sv[i].z * wv[k].z + sv[i].w * wv[k].w;
  }

  u16* tp = Tt + (size_t)b * 1048576;
#pragma unroll
  for (int k = 0; k < 8; ++k) {
    const int n = n0 + tn + 16 * k;
    ushort4 o;
    o.x = f2bf(acc[0][k]); o.y = f2bf(acc[1][k]);
    o.z = f2bf(acc[2][k]); o.w = f2bf(acc[3][k]);
    *(ushort4*)&tp[(size_t)n * 1024 + hh * 64 + td] = o;
  }
}

// ---------------------------------------------------------------------------
extern "C" void kernel_launch(void* const* d_in, const int* in_sizes, int n_in,
                              void* d_out, int out_size, void* d_ws, size_t ws_size,
                              hipStream_t stream) {
  const float* h  = (const float*)d_in[0];  // (4096, 1024) fp32
  // d_in[1] = key_pe: dead branch in reference, unused.
  const float* Wq = (const float*)d_in[2];
  const float* Wk = (const float*)d_in[3];
  const float* Wv = (const float*)d_in[4];
  const float* Wo = (const float*)d_in[5];

  char* ws = (char*)d_ws;
  u16*   hb    = (u16*)(ws);                    // 4096*1024*2 = 8 MiB @ 0
  u16*   wcat  = (u16*)(ws + (8ull  << 20));    // 3072*1024*2 = 6 MiB
  u16*   QKVb  = (u16*)(ws + (16ull << 20));    // 4096*3072*2 = 24 MiB
  float* S     = (float*)(ws + (40ull << 20));  // 32*64*64*4  = 0.5 MiB
  u16*   Tt    = (u16*)(ws + (41ull << 20));    // 2*1024*1024*2 = 4 MiB
  float* Spart = (float*)(ws + (48ull << 20));  // 512*64*64*4 = 8 MiB
  // total ws use: 56 MiB (ws_size = 256 MiB)

  prep<<<7168, 256, 0, stream>>>((const float4*)h, (const float4*)Wq,
                                 (const float4*)Wk, (const float4*)Wv,
                                 (ushort4*)hb, (ushort4*)wcat);
  // QKVb = hb @ wcat^T : (4096 x 3072), K=1024, 256 blocks = 1/CU, 8 waves
  gemm32<true, 384><<<256, 512, 0, stream>>>(hb, 1024, wcat, nullptr,
                                             QKVb, 3072);
  s_kernel<<<dim3(32, 16), 256, 0, stream>>>(QKVb, Spart);
  reduce_s<<<128, 256, 0, stream>>>((const float4*)Spart, (float4*)S);
  t_kernel<<<dim3(8, 16, 2), 256, 0, stream>>>(S, Wo, Tt);
  // out = Q @ Tt_b^T : (4096 x 1024), K=1024, 256 blocks = 1/CU, 8 waves
  gemm32<false, 128><<<256, 512, 0, stream>>>(QKVb, 3072, Tt, Tt + 1048576,
                                              d_out, 1024);
}